// Round 4
// baseline (1817.185 us; speedup 1.0000x reference)
//
#include <hip/hip_runtime.h>
#include <hip/hip_bf16.h>

// Sizes (fixed for this problem)
#define B_  4
#define S_  1024
#define DM_ 1024
#define H_  16
#define HD_ 64
#define I_  4096

__device__ __forceinline__ float gelu_f(float x) {
  float x3 = x * x * x;
  return 0.5f * x * (1.0f + tanhf(0.7978845608028654f * (x + 0.044715f * x3)));
}

__device__ __forceinline__ unsigned short f32_to_bf16(float f) {
  unsigned int u = __float_as_uint(f);
  unsigned int rounding = 0x7FFFu + ((u >> 16) & 1u);
  u += rounding;
  return (unsigned short)(u >> 16);
}

__device__ __forceinline__ float bf16_to_f32(unsigned short u) {
  return __uint_as_float(((unsigned int)u) << 16);
}

// ---------------------------------------------------------------------------
// Generic GEMM: C = [gelu](A @ W + bias) [+ res]
// A: [M,K] row-major (f32 or bf16), W: [K,N] row-major f32.
// 128x128 tile, 256 threads, 8x8 micro-tile in split {0..3,64..67} form.
// BHSD: store to [B,H,S,HD]. O_BF16: store bf16 (ws-internal only).
// ---------------------------------------------------------------------------
template<bool GELU, bool RES, bool BHSD, bool A_BF16, bool O_BF16>
__global__ __launch_bounds__(256) void gemm_f32_kernel(
    const void* __restrict__ Av, const float* __restrict__ W,
    const float* __restrict__ bias, const float* __restrict__ res,
    void* __restrict__ Cv, int M, int N, int K)
{
  __shared__ float As[16][132];   // transposed: As[k][m]
  __shared__ float Ws[16][132];   // Ws[k][n]
  const int tid = threadIdx.x;
  const int bm = blockIdx.y * 128;
  const int bn = blockIdx.x * 128;
  const int r0 = (tid >> 4) * 4;
  const int c0 = (tid & 15) * 4;

  float acc[8][8];
#pragma unroll
  for (int i = 0; i < 8; ++i)
#pragma unroll
    for (int j = 0; j < 8; ++j) acc[i][j] = 0.f;

  for (int k0 = 0; k0 < K; k0 += 16) {
#pragma unroll
    for (int i = 0; i < 2; ++i) {
      int idx = tid * 2 + i;          // 512 units: 128 rows x 4 quads
      int row = idx >> 2;
      int kq = (idx & 3) * 4;
      if (A_BF16) {
        const unsigned short* A16 = (const unsigned short*)Av;
        ushort4 a4 = *reinterpret_cast<const ushort4*>(&A16[(size_t)(bm + row) * K + (k0 + kq)]);
        As[kq + 0][row] = bf16_to_f32(a4.x);
        As[kq + 1][row] = bf16_to_f32(a4.y);
        As[kq + 2][row] = bf16_to_f32(a4.z);
        As[kq + 3][row] = bf16_to_f32(a4.w);
      } else {
        const float* A = (const float*)Av;
        float4 a4 = *reinterpret_cast<const float4*>(&A[(size_t)(bm + row) * K + (k0 + kq)]);
        As[kq + 0][row] = a4.x;
        As[kq + 1][row] = a4.y;
        As[kq + 2][row] = a4.z;
        As[kq + 3][row] = a4.w;
      }
    }
#pragma unroll
    for (int i = 0; i < 2; ++i) {
      int idx = tid * 2 + i;          // 512 float4 units: 16 k-rows x 32 f4
      int krow = idx >> 5;
      int nq = (idx & 31) * 4;
      *reinterpret_cast<float4*>(&Ws[krow][nq]) =
          *reinterpret_cast<const float4*>(&W[(size_t)(k0 + krow) * N + (bn + nq)]);
    }
    __syncthreads();
#pragma unroll
    for (int kk = 0; kk < 16; ++kk) {
      float a[8], w[8];
      *reinterpret_cast<float4*>(&a[0]) = *reinterpret_cast<const float4*>(&As[kk][r0]);
      *reinterpret_cast<float4*>(&a[4]) = *reinterpret_cast<const float4*>(&As[kk][r0 + 64]);
      *reinterpret_cast<float4*>(&w[0]) = *reinterpret_cast<const float4*>(&Ws[kk][c0]);
      *reinterpret_cast<float4*>(&w[4]) = *reinterpret_cast<const float4*>(&Ws[kk][c0 + 64]);
#pragma unroll
      for (int i = 0; i < 8; ++i)
#pragma unroll
        for (int j = 0; j < 8; ++j)
          acc[i][j] = fmaf(a[i], w[j], acc[i][j]);
    }
    __syncthreads();
  }

#pragma unroll
  for (int i = 0; i < 8; ++i) {
    int ri = bm + r0 + ((i < 4) ? i : 60 + i);
#pragma unroll
    for (int j = 0; j < 8; ++j) {
      int cj = bn + c0 + ((j < 4) ? j : 60 + j);
      float val = acc[i][j] + bias[cj];
      if (GELU) val = gelu_f(val);
      if (RES) val += res[(size_t)ri * N + cj];
      if (BHSD) {
        int bb = ri >> 10, ss = ri & 1023, hh = cj >> 6, dd = cj & 63;
        ((float*)Cv)[((size_t)(bb * H_ + hh) * S_ + ss) * HD_ + dd] = val;
      } else if (O_BF16) {
        ((unsigned short*)Cv)[(size_t)ri * N + cj] = f32_to_bf16(val);
      } else {
        ((float*)Cv)[(size_t)ri * N + cj] = val;
      }
    }
  }
}

// ---------------------------------------------------------------------------
// Fused attention scores + rel-position + mask + softmax -> probs (f32).
// One block per (b, h, 16 q-rows). Scores live in REGISTERS (64 f32/thread:
// thread (qg,kg) owns q-row qg, k in {kt*64 + kg + 16j}). LDS = 27.5 KB.
// ---------------------------------------------------------------------------
__global__ __launch_bounds__(256) void attn_kernel(
    const float* __restrict__ qk, const int* __restrict__ mask,
    const float* __restrict__ rel_emb, float* __restrict__ probs)
{
  __shared__ float Qs[16][68];
  __shared__ float Ks[64][68];
  __shared__ float relp[16][21];
  __shared__ float rsums[16];
  __shared__ float Pst[16][68];

  const int tid = threadIdx.x;
  const int b = blockIdx.z, h = blockIdx.y, qt = blockIdx.x;
  const float* qkbh = qk + (size_t)(b * H_ + h) * S_ * HD_;
  const int q0 = qt * 16;

  {  // Load 16x64 Q tile (256 float4 units)
    int row = tid >> 4, dq = (tid & 15) * 4;
    *reinterpret_cast<float4*>(&Qs[row][dq]) =
        *reinterpret_cast<const float4*>(&qkbh[(size_t)(q0 + row) * HD_ + dq]);
  }
  __syncthreads();

  // rel_proj[q][r] = Q[q,:] . rel_emb[r,:]
  for (int idx = tid; idx < 16 * 21; idx += 256) {
    int q = idx / 21, r = idx - q * 21;
    float s = 0.f;
#pragma unroll 8
    for (int d = 0; d < 64; ++d) s += Qs[q][d] * rel_emb[r * 64 + d];
    relp[q][r] = s;
  }

  const int qg = tid >> 4;   // q row 0..15
  const int kg = tid & 15;   // k cols {kt*64 + kg + 16j}
  const int qabs = q0 + qg;
  const int* mrow = mask + b * S_;

  float sreg[16][4];         // [kt][j] — fully unrolled, stays in VGPRs
  float mx = -3.0e38f;

#pragma unroll
  for (int kt = 0; kt < 16; ++kt) {
    __syncthreads();
#pragma unroll
    for (int i = 0; i < 4; ++i) {
      int idx = tid + i * 256;        // 1024 float4 units: 64 rows x 16 f4
      int row = idx >> 4, dq = (idx & 15) * 4;
      *reinterpret_cast<float4*>(&Ks[row][dq]) =
          *reinterpret_cast<const float4*>(&qkbh[(size_t)(kt * 64 + row) * HD_ + dq]);
    }
    __syncthreads();

    float acc[4] = {0.f, 0.f, 0.f, 0.f};
#pragma unroll 4
    for (int dq = 0; dq < 64; dq += 4) {
      float a[4];
      *reinterpret_cast<float4*>(a) = *reinterpret_cast<const float4*>(&Qs[qg][dq]);
#pragma unroll
      for (int j = 0; j < 4; ++j) {
        float kx[4];
        *reinterpret_cast<float4*>(kx) = *reinterpret_cast<const float4*>(&Ks[kg + 16 * j][dq]);
#pragma unroll
        for (int t = 0; t < 4; ++t) acc[j] = fmaf(a[t], kx[t], acc[j]);
      }
    }
#pragma unroll
    for (int j = 0; j < 4; ++j) {
      int k = kt * 64 + kg + 16 * j;
      int d = k - qabs;
      int ridx = (d < -10 ? -10 : (d > 10 ? 10 : d)) + 10;
      float s = acc[j] + relp[qg][ridx];
      if (k == qabs || mrow[k] == 0) s -= 10000.0f;
      sreg[kt][j] = s;
      mx = fmaxf(mx, s);
    }
  }

  // 16-lane row reductions (lanes of a q-row are contiguous within one wave)
  mx = fmaxf(mx, __shfl_xor(mx, 1));
  mx = fmaxf(mx, __shfl_xor(mx, 2));
  mx = fmaxf(mx, __shfl_xor(mx, 4));
  mx = fmaxf(mx, __shfl_xor(mx, 8));

  float sum = 0.f;
#pragma unroll
  for (int kt = 0; kt < 16; ++kt)
#pragma unroll
    for (int j = 0; j < 4; ++j) {
      float e = __expf(sreg[kt][j] - mx);
      sreg[kt][j] = e;
      sum += e;
    }
  sum += __shfl_xor(sum, 1);
  sum += __shfl_xor(sum, 2);
  sum += __shfl_xor(sum, 4);
  sum += __shfl_xor(sum, 8);
  if (kg == 0) rsums[qg] = 1.0f / sum;

  // Write probs (f32) via LDS staging for coalesced 256B-per-row stores
  float* prow = probs + (size_t)(b * H_ + h) * S_ * S_ + (size_t)q0 * S_;
#pragma unroll
  for (int kt = 0; kt < 16; ++kt) {
    __syncthreads();                  // first iter also publishes rsums
#pragma unroll
    for (int j = 0; j < 4; ++j) Pst[qg][kg + 16 * j] = sreg[kt][j];
    __syncthreads();
    int row = tid >> 4, c = (tid & 15) * 4;
    float rinv = rsums[row];
    float4 o;
    o.x = Pst[row][c + 0] * rinv;
    o.y = Pst[row][c + 1] * rinv;
    o.z = Pst[row][c + 2] * rinv;
    o.w = Pst[row][c + 3] * rinv;
    *reinterpret_cast<float4*>(&prow[(size_t)row * S_ + kt * 64 + c]) = o;
  }
}

// ---------------------------------------------------------------------------
// PV: ctx[b, q, h*64+d] = sum_k probs[b,h,q,k] * v[b,h,k,d]   (probs f32)
// Block: 128 q-rows x 64 d for one (b,h). LDS = 12.8 KB.
// ---------------------------------------------------------------------------
__global__ __launch_bounds__(256) void pv_kernel(
    const float* __restrict__ probs, const float* __restrict__ v,
    float* __restrict__ ctx)
{
  __shared__ float Ps[16][132];   // [k][q] transposed
  __shared__ float Vs[16][68];    // [k][d]
  const int tid = threadIdx.x;
  const int b = blockIdx.z, h = blockIdx.y, qt = blockIdx.x;
  const float* pr = probs + (size_t)(b * H_ + h) * S_ * S_ + (size_t)qt * 128 * S_;
  const float* vbh = v + (size_t)(b * H_ + h) * S_ * HD_;
  const int r0 = (tid >> 4) * 4;
  const int c0 = (tid & 15) * 4;

  float acc[8][4];
#pragma unroll
  for (int i = 0; i < 8; ++i)
#pragma unroll
    for (int j = 0; j < 4; ++j) acc[i][j] = 0.f;

  for (int k0 = 0; k0 < S_; k0 += 16) {
#pragma unroll
    for (int i = 0; i < 2; ++i) {
      int idx = tid * 2 + i;          // 512 float4 units: 128 rows x 4
      int row = idx >> 2, kq = (idx & 3) * 4;
      float4 u = *reinterpret_cast<const float4*>(&pr[(size_t)row * S_ + k0 + kq]);
      Ps[kq + 0][row] = u.x;
      Ps[kq + 1][row] = u.y;
      Ps[kq + 2][row] = u.z;
      Ps[kq + 3][row] = u.w;
    }
    {
      int krow = tid >> 4, dq = (tid & 15) * 4;
      *reinterpret_cast<float4*>(&Vs[krow][dq]) =
          *reinterpret_cast<const float4*>(&vbh[(size_t)(k0 + krow) * HD_ + dq]);
    }
    __syncthreads();
#pragma unroll
    for (int kk = 0; kk < 16; ++kk) {
      float a[8], w[4];
      *reinterpret_cast<float4*>(&a[0]) = *reinterpret_cast<const float4*>(&Ps[kk][r0]);
      *reinterpret_cast<float4*>(&a[4]) = *reinterpret_cast<const float4*>(&Ps[kk][r0 + 64]);
      *reinterpret_cast<float4*>(&w[0]) = *reinterpret_cast<const float4*>(&Vs[kk][c0]);
#pragma unroll
      for (int i = 0; i < 8; ++i)
#pragma unroll
        for (int j = 0; j < 4; ++j)
          acc[i][j] = fmaf(a[i], w[j], acc[i][j]);
    }
    __syncthreads();
  }

#pragma unroll
  for (int i = 0; i < 8; ++i) {
    int q = qt * 128 + r0 + ((i < 4) ? i : 60 + i);
    float4 o = make_float4(acc[i][0], acc[i][1], acc[i][2], acc[i][3]);
    *reinterpret_cast<float4*>(&ctx[((size_t)b * S_ + q) * DM_ + h * HD_ + c0]) = o;
  }
}

// ---------------------------------------------------------------------------
// Row LayerNorm (1024 cols), f32 in / f32 out
// ---------------------------------------------------------------------------
__global__ __launch_bounds__(256) void ln_kernel(
    const float* __restrict__ in, const float* __restrict__ g,
    const float* __restrict__ be, float* __restrict__ out)
{
  __shared__ float red[4];
  const int row = blockIdx.x, tid = threadIdx.x;
  const float* r = in + (size_t)row * DM_;
  float4 x = *reinterpret_cast<const float4*>(&r[tid * 4]);

  float s = x.x + x.y + x.z + x.w;
#pragma unroll
  for (int m = 1; m < 64; m <<= 1) s += __shfl_xor(s, m);
  if ((tid & 63) == 0) red[tid >> 6] = s;
  __syncthreads();
  float mean = (red[0] + red[1] + red[2] + red[3]) * (1.0f / 1024.0f);
  __syncthreads();

  float d0 = x.x - mean, d1 = x.y - mean, d2 = x.z - mean, d3 = x.w - mean;
  float sq = d0 * d0 + d1 * d1 + d2 * d2 + d3 * d3;
#pragma unroll
  for (int m = 1; m < 64; m <<= 1) sq += __shfl_xor(sq, m);
  if ((tid & 63) == 0) red[tid >> 6] = sq;
  __syncthreads();
  float var = (red[0] + red[1] + red[2] + red[3]) * (1.0f / 1024.0f);
  float rstd = rsqrtf(var + 1e-3f);

  int c = tid * 4;
  float4 gv = *reinterpret_cast<const float4*>(&g[c]);
  float4 bv = *reinterpret_cast<const float4*>(&be[c]);
  float4 o;
  o.x = d0 * rstd * gv.x + bv.x;
  o.y = d1 * rstd * gv.y + bv.y;
  o.z = d2 * rstd * gv.z + bv.z;
  o.w = d3 * rstd * gv.w + bv.w;
  *reinterpret_cast<float4*>(&out[(size_t)row * DM_ + c]) = o;
}

// ---------------------------------------------------------------------------
// Workspace: 64 MB = 4 slots of 4,194,304 floats (16 MB each).
//   S0: qkb -> attn      S1: vb -> t      S2: ctx -> inter(lo)   S3: y -> inter(hi)
// inter is bf16 [4096,4096] = 32 MB spanning S2..S3 (both dead by then).
// d_out is FLOAT32: out [B,S,DM] then probs [B,H,S,S], concatenated.
// ---------------------------------------------------------------------------
extern "C" void kernel_launch(void* const* d_in, const int* in_sizes, int n_in,
                              void* d_out, int out_size, void* d_ws, size_t ws_size,
                              hipStream_t stream) {
  const float* x    = (const float*)d_in[0];
  const int*   mask = (const int*)d_in[1];
  const float* Wqk  = (const float*)d_in[2];
  const float* bqk  = (const float*)d_in[3];
  const float* Wv   = (const float*)d_in[4];
  const float* bv   = (const float*)d_in[5];
  const float* rel  = (const float*)d_in[6];
  const float* Wap  = (const float*)d_in[7];
  const float* bap  = (const float*)d_in[8];
  const float* g1   = (const float*)d_in[9];
  const float* b1   = (const float*)d_in[10];
  const float* Wi   = (const float*)d_in[11];
  const float* bi   = (const float*)d_in[12];
  const float* Wo   = (const float*)d_in[13];
  const float* bo   = (const float*)d_in[14];
  const float* g2   = (const float*)d_in[15];
  const float* b2   = (const float*)d_in[16];

  float* ws = (float*)d_ws;
  float* S0f = ws;
  float* S1f = ws + 4194304;
  float* S2f = ws + 8388608;
  float* S3f = ws + 12582912;

  float* qkb  = S0f;
  float* vb   = S1f;
  float* ctx  = S2f;
  float* y    = S3f;
  float* attn = S0f;                              // qkb dead after attn_kernel
  unsigned short* interb = (unsigned short*)S2f;  // 16M bf16 over S2..S3
  float* t    = S1f;                              // vb dead after pv_kernel

  float* outf  = (float*)d_out;                   // out   [B,S,DM]  f32
  float* probs = outf + 4194304;                  // probs [B,H,S,S] f32

  dim3 blk(256);
  // q/k shared projection and v projection -> [B,H,S,HD] (f32)
  gemm_f32_kernel<false, false, true, false, false><<<dim3(8, 32), blk, 0, stream>>>(
      x, Wqk, bqk, nullptr, qkb, 4096, 1024, 1024);
  gemm_f32_kernel<false, false, true, false, false><<<dim3(8, 32), blk, 0, stream>>>(
      x, Wv, bv, nullptr, vb, 4096, 1024, 1024);
  // scores + rel + mask + softmax -> probs (f32, second output)
  attn_kernel<<<dim3(64, 16, 4), blk, 0, stream>>>(qkb, mask, rel, probs);
  // ctx = probs @ v -> [B,S,DM]
  pv_kernel<<<dim3(8, 16, 4), blk, 0, stream>>>(probs, vb, ctx);
  // y = gelu(ctx @ Wap + bap) + x
  gemm_f32_kernel<true, true, false, false, false><<<dim3(8, 32), blk, 0, stream>>>(
      ctx, Wap, bap, x, y, 4096, 1024, 1024);
  // attn = LN(y)*g1+b1
  ln_kernel<<<4096, blk, 0, stream>>>(y, g1, b1, attn);
  // inter = gelu(attn @ Wi + bi)  (bf16, ws-internal)
  gemm_f32_kernel<true, false, false, false, true><<<dim3(32, 32), blk, 0, stream>>>(
      attn, Wi, bi, nullptr, interb, 4096, 4096, 1024);
  // t = gelu(inter @ Wo + bo) + attn
  gemm_f32_kernel<true, true, false, true, false><<<dim3(8, 32), blk, 0, stream>>>(
      interb, Wo, bo, attn, t, 4096, 1024, 4096);
  // out = LN(t)*g2+b2 (f32)
  ln_kernel<<<4096, blk, 0, stream>>>(t, g2, b2, outf);
}

// Round 5
// 886.726 us; speedup vs baseline: 2.0493x; 2.0493x over previous
//
#include <hip/hip_runtime.h>
#include <hip/hip_bf16.h>

// Sizes (fixed for this problem)
#define B_  4
#define S_  1024
#define DM_ 1024
#define H_  16
#define HD_ 64
#define I_  4096

typedef __attribute__((ext_vector_type(8))) short bf16x8;
typedef __attribute__((ext_vector_type(4))) float f32x4;

__device__ __forceinline__ float gelu_f(float x) {
  float x3 = x * x * x;
  return 0.5f * x * (1.0f + tanhf(0.7978845608028654f * (x + 0.044715f * x3)));
}

__device__ __forceinline__ unsigned short f32_to_bf16(float f) {
  unsigned int u = __float_as_uint(f);
  unsigned int rounding = 0x7FFFu + ((u >> 16) & 1u);
  u += rounding;
  return (unsigned short)(u >> 16);
}

__device__ __forceinline__ float bf16_to_f32(unsigned short u) {
  return __uint_as_float(((unsigned int)u) << 16);
}

// ---------------------------------------------------------------------------
// f32 -> bf16 elementwise convert (for x)
// ---------------------------------------------------------------------------
__global__ __launch_bounds__(256) void cvt_bf16_kernel(
    const float* __restrict__ in, unsigned short* __restrict__ out, int n4)
{
  int i = blockIdx.x * 256 + threadIdx.x;
  if (i < n4) {
    float4 v = *reinterpret_cast<const float4*>(&in[(size_t)i * 4]);
    ushort4 o;
    o.x = f32_to_bf16(v.x); o.y = f32_to_bf16(v.y);
    o.z = f32_to_bf16(v.z); o.w = f32_to_bf16(v.w);
    *reinterpret_cast<ushort4*>(&out[(size_t)i * 4]) = o;
  }
}

// ---------------------------------------------------------------------------
// Transpose + convert: W [K,N] f32 -> WT [N,K] bf16. 64x64 tiles, 256 thr.
// ---------------------------------------------------------------------------
__global__ __launch_bounds__(256) void tcvt_kernel(
    const float* __restrict__ W, unsigned short* __restrict__ WT, int K, int N)
{
  __shared__ float tile[64][65];
  const int tid = threadIdx.x;
  const int k0 = blockIdx.y * 64, n0 = blockIdx.x * 64;
#pragma unroll
  for (int i = 0; i < 4; ++i) {
    int u = tid + i * 256;            // 1024 float4 units: 64 rows x 16
    int kr = u >> 4, nc = (u & 15) * 4;
    float4 v = *reinterpret_cast<const float4*>(&W[(size_t)(k0 + kr) * N + n0 + nc]);
    tile[kr][nc + 0] = v.x; tile[kr][nc + 1] = v.y;
    tile[kr][nc + 2] = v.z; tile[kr][nc + 3] = v.w;
  }
  __syncthreads();
  // each thread writes 16 bf16 (32B) of one WT row
  int n = tid >> 2, ks = (tid & 3) * 16;
  ushort4 o[4];
#pragma unroll
  for (int j = 0; j < 4; ++j) {
    o[j].x = f32_to_bf16(tile[ks + j * 4 + 0][n]);
    o[j].y = f32_to_bf16(tile[ks + j * 4 + 1][n]);
    o[j].z = f32_to_bf16(tile[ks + j * 4 + 2][n]);
    o[j].w = f32_to_bf16(tile[ks + j * 4 + 3][n]);
  }
  unsigned short* dst = &WT[(size_t)(n0 + n) * K + k0 + ks];
#pragma unroll
  for (int j = 0; j < 4; ++j)
    *reinterpret_cast<ushort4*>(&dst[j * 4]) = o[j];
}

// ---------------------------------------------------------------------------
// bf16 MFMA GEMM: C = [gelu](A @ B + bias) [+ res]
// A [M,K] bf16 row-major; BT [N,K] bf16 row-major (pre-transposed B).
// 128x128 tile, BK=32, 256 thr = 4 waves; wave computes 32 rows x 128 cols
// (2x8 fragments of v_mfma_f32_16x16x32_bf16). LDS rows padded to 40 ushorts
// (80B = 20 banks -> 2-way aliasing, free).
// ---------------------------------------------------------------------------
template<bool GELU, bool RES, bool RESBF16, bool BHSD, bool OBF16>
__global__ __launch_bounds__(256) void gemm_mfma_kernel(
    const unsigned short* __restrict__ A, const unsigned short* __restrict__ BT,
    const float* __restrict__ bias, const void* __restrict__ res,
    void* __restrict__ C, int M, int N, int K)
{
  __shared__ unsigned short As[128][40];
  __shared__ unsigned short Bs[128][40];
  const int tid = threadIdx.x;
  const int wid = tid >> 6;
  const int lane = tid & 63;
  const int bm = blockIdx.y * 128;
  const int bn = blockIdx.x * 128;
  const int l15 = lane & 15;
  const int kb = (lane >> 4) * 8;   // k-subblock within BK=32

  f32x4 acc[2][8];
#pragma unroll
  for (int mi = 0; mi < 2; ++mi)
#pragma unroll
    for (int ni = 0; ni < 8; ++ni) acc[mi][ni] = (f32x4){0.f, 0.f, 0.f, 0.f};

  for (int k0 = 0; k0 < K; k0 += 32) {
#pragma unroll
    for (int i = 0; i < 2; ++i) {
      int u = tid + i * 256;          // 512 16B units: 128 rows x 4 segs
      int row = u >> 2, seg = (u & 3) * 8;
      int4 va = *reinterpret_cast<const int4*>(&A[(size_t)(bm + row) * K + k0 + seg]);
      *reinterpret_cast<int4*>(&As[row][seg]) = va;
      int4 vb = *reinterpret_cast<const int4*>(&BT[(size_t)(bn + row) * K + k0 + seg]);
      *reinterpret_cast<int4*>(&Bs[row][seg]) = vb;
    }
    __syncthreads();

    bf16x8 af[2], bf[8];
#pragma unroll
    for (int mi = 0; mi < 2; ++mi)
      af[mi] = *reinterpret_cast<const bf16x8*>(&As[wid * 32 + mi * 16 + l15][kb]);
#pragma unroll
    for (int ni = 0; ni < 8; ++ni)
      bf[ni] = *reinterpret_cast<const bf16x8*>(&Bs[ni * 16 + l15][kb]);
#pragma unroll
    for (int mi = 0; mi < 2; ++mi)
#pragma unroll
      for (int ni = 0; ni < 8; ++ni)
        acc[mi][ni] = __builtin_amdgcn_mfma_f32_16x16x32_bf16(
            af[mi], bf[ni], acc[mi][ni], 0, 0, 0);
    __syncthreads();
  }

  // Epilogue: D row = (lane>>4)*4 + r, col = lane&15 within each fragment
#pragma unroll
  for (int mi = 0; mi < 2; ++mi) {
#pragma unroll
    for (int ni = 0; ni < 8; ++ni) {
      int gcol = bn + ni * 16 + l15;
      float bsv = bias[gcol];
#pragma unroll
      for (int r = 0; r < 4; ++r) {
        int grow = bm + wid * 32 + mi * 16 + (lane >> 4) * 4 + r;
        float val = acc[mi][ni][r] + bsv;
        if (GELU) val = gelu_f(val);
        if (RES) {
          if (RESBF16) val += bf16_to_f32(((const unsigned short*)res)[(size_t)grow * N + gcol]);
          else         val += ((const float*)res)[(size_t)grow * N + gcol];
        }
        if (BHSD) {  // [B,H,S,HD] f32 scatter (v projection)
          int bb = grow >> 10, ss = grow & 1023, hh = gcol >> 6, dd = gcol & 63;
          ((float*)C)[((size_t)(bb * H_ + hh) * S_ + ss) * HD_ + dd] = val;
        } else if (OBF16) {
          ((unsigned short*)C)[(size_t)grow * N + gcol] = f32_to_bf16(val);
        } else {
          ((float*)C)[(size_t)grow * N + gcol] = val;
        }
      }
    }
  }
}

// ---------------------------------------------------------------------------
// fp32 GEMM (kept for the probs-critical q/k projection only).
// ---------------------------------------------------------------------------
__global__ __launch_bounds__(256) void gemm_f32_bhsd_kernel(
    const float* __restrict__ A, const float* __restrict__ W,
    const float* __restrict__ bias, float* __restrict__ C, int M, int N, int K)
{
  __shared__ float As[16][132];
  __shared__ float Ws[16][132];
  const int tid = threadIdx.x;
  const int bm = blockIdx.y * 128;
  const int bn = blockIdx.x * 128;
  const int r0 = (tid >> 4) * 4;
  const int c0 = (tid & 15) * 4;

  float acc[8][8];
#pragma unroll
  for (int i = 0; i < 8; ++i)
#pragma unroll
    for (int j = 0; j < 8; ++j) acc[i][j] = 0.f;

  for (int k0 = 0; k0 < K; k0 += 16) {
#pragma unroll
    for (int i = 0; i < 2; ++i) {
      int idx = tid * 2 + i;
      int row = idx >> 2;
      int kq = (idx & 3) * 4;
      float4 a4 = *reinterpret_cast<const float4*>(&A[(size_t)(bm + row) * K + (k0 + kq)]);
      As[kq + 0][row] = a4.x;
      As[kq + 1][row] = a4.y;
      As[kq + 2][row] = a4.z;
      As[kq + 3][row] = a4.w;
    }
#pragma unroll
    for (int i = 0; i < 2; ++i) {
      int idx = tid * 2 + i;
      int krow = idx >> 5;
      int nq = (idx & 31) * 4;
      *reinterpret_cast<float4*>(&Ws[krow][nq]) =
          *reinterpret_cast<const float4*>(&W[(size_t)(k0 + krow) * N + (bn + nq)]);
    }
    __syncthreads();
#pragma unroll
    for (int kk = 0; kk < 16; ++kk) {
      float a[8], w[8];
      *reinterpret_cast<float4*>(&a[0]) = *reinterpret_cast<const float4*>(&As[kk][r0]);
      *reinterpret_cast<float4*>(&a[4]) = *reinterpret_cast<const float4*>(&As[kk][r0 + 64]);
      *reinterpret_cast<float4*>(&w[0]) = *reinterpret_cast<const float4*>(&Ws[kk][c0]);
      *reinterpret_cast<float4*>(&w[4]) = *reinterpret_cast<const float4*>(&Ws[kk][c0 + 64]);
#pragma unroll
      for (int i = 0; i < 8; ++i)
#pragma unroll
        for (int j = 0; j < 8; ++j)
          acc[i][j] = fmaf(a[i], w[j], acc[i][j]);
    }
    __syncthreads();
  }

#pragma unroll
  for (int i = 0; i < 8; ++i) {
    int ri = bm + r0 + ((i < 4) ? i : 60 + i);
#pragma unroll
    for (int j = 0; j < 8; ++j) {
      int cj = bn + c0 + ((j < 4) ? j : 60 + j);
      float val = acc[i][j] + bias[cj];
      int bb = ri >> 10, ss = ri & 1023, hh = cj >> 6, dd = cj & 63;
      C[((size_t)(bb * H_ + hh) * S_ + ss) * HD_ + dd] = val;
    }
  }
}

// ---------------------------------------------------------------------------
// Fused attention scores + rel-position + mask + softmax -> probs (f32).
// One block per (b, h, 16 q-rows); scores in registers. LDS = 27.5 KB.
// ---------------------------------------------------------------------------
__global__ __launch_bounds__(256) void attn_kernel(
    const float* __restrict__ qk, const int* __restrict__ mask,
    const float* __restrict__ rel_emb, float* __restrict__ probs)
{
  __shared__ float Qs[16][68];
  __shared__ float Ks[64][68];
  __shared__ float relp[16][21];
  __shared__ float rsums[16];
  __shared__ float Pst[16][68];

  const int tid = threadIdx.x;
  const int b = blockIdx.z, h = blockIdx.y, qt = blockIdx.x;
  const float* qkbh = qk + (size_t)(b * H_ + h) * S_ * HD_;
  const int q0 = qt * 16;

  {
    int row = tid >> 4, dq = (tid & 15) * 4;
    *reinterpret_cast<float4*>(&Qs[row][dq]) =
        *reinterpret_cast<const float4*>(&qkbh[(size_t)(q0 + row) * HD_ + dq]);
  }
  __syncthreads();

  for (int idx = tid; idx < 16 * 21; idx += 256) {
    int q = idx / 21, r = idx - q * 21;
    float s = 0.f;
#pragma unroll 8
    for (int d = 0; d < 64; ++d) s += Qs[q][d] * rel_emb[r * 64 + d];
    relp[q][r] = s;
  }

  const int qg = tid >> 4;
  const int kg = tid & 15;
  const int qabs = q0 + qg;
  const int* mrow = mask + b * S_;

  float sreg[16][4];
  float mx = -3.0e38f;

#pragma unroll
  for (int kt = 0; kt < 16; ++kt) {
    __syncthreads();
#pragma unroll
    for (int i = 0; i < 4; ++i) {
      int idx = tid + i * 256;
      int row = idx >> 4, dq = (idx & 15) * 4;
      *reinterpret_cast<float4*>(&Ks[row][dq]) =
          *reinterpret_cast<const float4*>(&qkbh[(size_t)(kt * 64 + row) * HD_ + dq]);
    }
    __syncthreads();

    float acc[4] = {0.f, 0.f, 0.f, 0.f};
#pragma unroll 4
    for (int dq = 0; dq < 64; dq += 4) {
      float a[4];
      *reinterpret_cast<float4*>(a) = *reinterpret_cast<const float4*>(&Qs[qg][dq]);
#pragma unroll
      for (int j = 0; j < 4; ++j) {
        float kx[4];
        *reinterpret_cast<float4*>(kx) = *reinterpret_cast<const float4*>(&Ks[kg + 16 * j][dq]);
#pragma unroll
        for (int t = 0; t < 4; ++t) acc[j] = fmaf(a[t], kx[t], acc[j]);
      }
    }
#pragma unroll
    for (int j = 0; j < 4; ++j) {
      int k = kt * 64 + kg + 16 * j;
      int d = k - qabs;
      int ridx = (d < -10 ? -10 : (d > 10 ? 10 : d)) + 10;
      float s = acc[j] + relp[qg][ridx];
      if (k == qabs || mrow[k] == 0) s -= 10000.0f;
      sreg[kt][j] = s;
      mx = fmaxf(mx, s);
    }
  }

  mx = fmaxf(mx, __shfl_xor(mx, 1));
  mx = fmaxf(mx, __shfl_xor(mx, 2));
  mx = fmaxf(mx, __shfl_xor(mx, 4));
  mx = fmaxf(mx, __shfl_xor(mx, 8));

  float sum = 0.f;
#pragma unroll
  for (int kt = 0; kt < 16; ++kt)
#pragma unroll
    for (int j = 0; j < 4; ++j) {
      float e = __expf(sreg[kt][j] - mx);
      sreg[kt][j] = e;
      sum += e;
    }
  sum += __shfl_xor(sum, 1);
  sum += __shfl_xor(sum, 2);
  sum += __shfl_xor(sum, 4);
  sum += __shfl_xor(sum, 8);
  if (kg == 0) rsums[qg] = 1.0f / sum;

  float* prow = probs + (size_t)(b * H_ + h) * S_ * S_ + (size_t)q0 * S_;
#pragma unroll
  for (int kt = 0; kt < 16; ++kt) {
    __syncthreads();
#pragma unroll
    for (int j = 0; j < 4; ++j) Pst[qg][kg + 16 * j] = sreg[kt][j];
    __syncthreads();
    int row = tid >> 4, c = (tid & 15) * 4;
    float rinv = rsums[row];
    float4 o;
    o.x = Pst[row][c + 0] * rinv;
    o.y = Pst[row][c + 1] * rinv;
    o.z = Pst[row][c + 2] * rinv;
    o.w = Pst[row][c + 3] * rinv;
    *reinterpret_cast<float4*>(&prow[(size_t)row * S_ + kt * 64 + c]) = o;
  }
}

// ---------------------------------------------------------------------------
// PV: ctxb[b, q, h*64+d] = sum_k probs[b,h,q,k] * v[b,h,k,d]  -> bf16 out
// ---------------------------------------------------------------------------
__global__ __launch_bounds__(256) void pv_kernel(
    const float* __restrict__ probs, const float* __restrict__ v,
    unsigned short* __restrict__ ctxb)
{
  __shared__ float Ps[16][132];
  __shared__ float Vs[16][68];
  const int tid = threadIdx.x;
  const int b = blockIdx.z, h = blockIdx.y, qt = blockIdx.x;
  const float* pr = probs + (size_t)(b * H_ + h) * S_ * S_ + (size_t)qt * 128 * S_;
  const float* vbh = v + (size_t)(b * H_ + h) * S_ * HD_;
  const int r0 = (tid >> 4) * 4;
  const int c0 = (tid & 15) * 4;

  float acc[8][4];
#pragma unroll
  for (int i = 0; i < 8; ++i)
#pragma unroll
    for (int j = 0; j < 4; ++j) acc[i][j] = 0.f;

  for (int k0 = 0; k0 < S_; k0 += 16) {
#pragma unroll
    for (int i = 0; i < 2; ++i) {
      int idx = tid * 2 + i;
      int row = idx >> 2, kq = (idx & 3) * 4;
      float4 u = *reinterpret_cast<const float4*>(&pr[(size_t)row * S_ + k0 + kq]);
      Ps[kq + 0][row] = u.x;
      Ps[kq + 1][row] = u.y;
      Ps[kq + 2][row] = u.z;
      Ps[kq + 3][row] = u.w;
    }
    {
      int krow = tid >> 4, dq = (tid & 15) * 4;
      *reinterpret_cast<float4*>(&Vs[krow][dq]) =
          *reinterpret_cast<const float4*>(&vbh[(size_t)(k0 + krow) * HD_ + dq]);
    }
    __syncthreads();
#pragma unroll
    for (int kk = 0; kk < 16; ++kk) {
      float a[8], w[4];
      *reinterpret_cast<float4*>(&a[0]) = *reinterpret_cast<const float4*>(&Ps[kk][r0]);
      *reinterpret_cast<float4*>(&a[4]) = *reinterpret_cast<const float4*>(&Ps[kk][r0 + 64]);
      *reinterpret_cast<float4*>(&w[0]) = *reinterpret_cast<const float4*>(&Vs[kk][c0]);
#pragma unroll
      for (int i = 0; i < 8; ++i)
#pragma unroll
        for (int j = 0; j < 4; ++j)
          acc[i][j] = fmaf(a[i], w[j], acc[i][j]);
    }
    __syncthreads();
  }

#pragma unroll
  for (int i = 0; i < 8; ++i) {
    int q = qt * 128 + r0 + ((i < 4) ? i : 60 + i);
    ushort4 o;
    o.x = f32_to_bf16(acc[i][0]);
    o.y = f32_to_bf16(acc[i][1]);
    o.z = f32_to_bf16(acc[i][2]);
    o.w = f32_to_bf16(acc[i][3]);
    *reinterpret_cast<ushort4*>(&ctxb[((size_t)b * S_ + q) * DM_ + h * HD_ + c0]) = o;
  }
}

// ---------------------------------------------------------------------------
// Row LayerNorm (1024 cols), f32 in, f32 or bf16 out
// ---------------------------------------------------------------------------
template<bool OUTB16>
__global__ __launch_bounds__(256) void ln_kernel(
    const float* __restrict__ in, const float* __restrict__ g,
    const float* __restrict__ be, void* __restrict__ out)
{
  __shared__ float red[4];
  const int row = blockIdx.x, tid = threadIdx.x;
  const float* r = in + (size_t)row * DM_;
  float4 x = *reinterpret_cast<const float4*>(&r[tid * 4]);

  float s = x.x + x.y + x.z + x.w;
#pragma unroll
  for (int m = 1; m < 64; m <<= 1) s += __shfl_xor(s, m);
  if ((tid & 63) == 0) red[tid >> 6] = s;
  __syncthreads();
  float mean = (red[0] + red[1] + red[2] + red[3]) * (1.0f / 1024.0f);
  __syncthreads();

  float d0 = x.x - mean, d1 = x.y - mean, d2 = x.z - mean, d3 = x.w - mean;
  float sq = d0 * d0 + d1 * d1 + d2 * d2 + d3 * d3;
#pragma unroll
  for (int m = 1; m < 64; m <<= 1) sq += __shfl_xor(sq, m);
  if ((tid & 63) == 0) red[tid >> 6] = sq;
  __syncthreads();
  float var = (red[0] + red[1] + red[2] + red[3]) * (1.0f / 1024.0f);
  float rstd = rsqrtf(var + 1e-3f);

  int c = tid * 4;
  float4 gv = *reinterpret_cast<const float4*>(&g[c]);
  float4 bv = *reinterpret_cast<const float4*>(&be[c]);
  float y0 = d0 * rstd * gv.x + bv.x;
  float y1 = d1 * rstd * gv.y + bv.y;
  float y2 = d2 * rstd * gv.z + bv.z;
  float y3 = d3 * rstd * gv.w + bv.w;
  if (OUTB16) {
    ushort4 o;
    o.x = f32_to_bf16(y0); o.y = f32_to_bf16(y1);
    o.z = f32_to_bf16(y2); o.w = f32_to_bf16(y3);
    *reinterpret_cast<ushort4*>(&((unsigned short*)out)[(size_t)row * DM_ + c]) = o;
  } else {
    *reinterpret_cast<float4*>(&((float*)out)[(size_t)row * DM_ + c]) =
        make_float4(y0, y1, y2, y3);
  }
}

// ---------------------------------------------------------------------------
// Workspace plan (64 MB exactly, lifetime-checked overlays; offsets in MB):
//   0-8   WoT bf16            (start -> Wo)
//   8-16  xb bf16 (->Wv) then ctxb bf16 (pv -> Wap)
//   16-18 WvT bf16 (-> Wv)
//   18-20 WapT bf16 (-> Wap)
//   20-36 qkb f32 (-> attn) then y f32 (Wap -> ln1)
//   40-56 vb f32 (Wv -> pv)
//   40-48 attnb bf16 (ln1 -> Wo res)
//   56-64 WiT bf16 (start -> Wi)
//   8-40  interb bf16 (Wi -> Wo)
//   48-64 t f32 (Wo -> ln2)
// ---------------------------------------------------------------------------
extern "C" void kernel_launch(void* const* d_in, const int* in_sizes, int n_in,
                              void* d_out, int out_size, void* d_ws, size_t ws_size,
                              hipStream_t stream) {
  const float* x    = (const float*)d_in[0];
  const int*   mask = (const int*)d_in[1];
  const float* Wqk  = (const float*)d_in[2];
  const float* bqk  = (const float*)d_in[3];
  const float* Wv   = (const float*)d_in[4];
  const float* bv   = (const float*)d_in[5];
  const float* rel  = (const float*)d_in[6];
  const float* Wap  = (const float*)d_in[7];
  const float* bap  = (const float*)d_in[8];
  const float* g1   = (const float*)d_in[9];
  const float* b1   = (const float*)d_in[10];
  const float* Wi   = (const float*)d_in[11];
  const float* bi   = (const float*)d_in[12];
  const float* Wo   = (const float*)d_in[13];
  const float* bo   = (const float*)d_in[14];
  const float* g2   = (const float*)d_in[15];
  const float* b2   = (const float*)d_in[16];

  char* wsb = (char*)d_ws;
  const size_t MB = 1048576;
  unsigned short* WoT    = (unsigned short*)(wsb + 0 * MB);
  unsigned short* xb     = (unsigned short*)(wsb + 8 * MB);
  unsigned short* ctxb   = (unsigned short*)(wsb + 8 * MB);
  unsigned short* WvT    = (unsigned short*)(wsb + 16 * MB);
  unsigned short* WapT   = (unsigned short*)(wsb + 18 * MB);
  float*          qkb    = (float*)(wsb + 20 * MB);
  float*          y      = (float*)(wsb + 20 * MB);
  float*          vb     = (float*)(wsb + 40 * MB);
  unsigned short* attnb  = (unsigned short*)(wsb + 40 * MB);
  unsigned short* WiT    = (unsigned short*)(wsb + 56 * MB);
  unsigned short* interb = (unsigned short*)(wsb + 8 * MB);
  float*          t      = (float*)(wsb + 48 * MB);

  float* outf  = (float*)d_out;        // out   [B,S,DM]  f32
  float* probs = outf + 4194304;       // probs [B,H,S,S] f32

  dim3 blk(256);
  // Converts / transposes (bf16 weights for MFMA path)
  cvt_bf16_kernel<<<4096, blk, 0, stream>>>(x, xb, 1048576);
  tcvt_kernel<<<dim3(16, 16), blk, 0, stream>>>(Wv,  WvT,  1024, 1024);
  tcvt_kernel<<<dim3(16, 16), blk, 0, stream>>>(Wap, WapT, 1024, 1024);
  tcvt_kernel<<<dim3(64, 16), blk, 0, stream>>>(Wi,  WiT,  1024, 4096);
  tcvt_kernel<<<dim3(16, 64), blk, 0, stream>>>(Wo,  WoT,  4096, 1024);

  // q/k shared projection (fp32 — probs-critical) -> [B,H,S,HD]
  gemm_f32_bhsd_kernel<<<dim3(8, 32), blk, 0, stream>>>(
      x, Wqk, bqk, qkb, 4096, 1024, 1024);
  // v projection (bf16 MFMA) -> [B,H,S,HD] f32
  gemm_mfma_kernel<false, false, false, true, false><<<dim3(8, 32), blk, 0, stream>>>(
      xb, WvT, bv, nullptr, vb, 4096, 1024, 1024);
  // scores + rel + mask + softmax -> probs (f32, second output)
  attn_kernel<<<dim3(64, 16, 4), blk, 0, stream>>>(qkb, mask, rel, probs);
  // ctx = probs @ v -> bf16 [B,S,DM]
  pv_kernel<<<dim3(8, 16, 4), blk, 0, stream>>>(probs, vb, ctxb);
  // y = gelu(ctx @ Wap + bap) + x  (MFMA, res = x f32)
  gemm_mfma_kernel<true, true, false, false, false><<<dim3(8, 32), blk, 0, stream>>>(
      ctxb, WapT, bap, x, y, 4096, 1024, 1024);
  // attnb = LN(y)*g1+b1 (bf16)
  ln_kernel<true><<<4096, blk, 0, stream>>>(y, g1, b1, attnb);
  // inter = gelu(attn @ Wi + bi) (MFMA, bf16 out)
  gemm_mfma_kernel<true, false, false, false, true><<<dim3(32, 32), blk, 0, stream>>>(
      attnb, WiT, bi, nullptr, interb, 4096, 4096, 1024);
  // t = gelu(inter @ Wo + bo) + attn (MFMA, res = attnb bf16)
  gemm_mfma_kernel<true, true, true, false, false><<<dim3(8, 32), blk, 0, stream>>>(
      interb, WoT, bo, attnb, t, 4096, 1024, 4096);
  // out = LN(t)*g2+b2 (f32)
  ln_kernel<false><<<4096, blk, 0, stream>>>(t, g2, b2, outf);
}

// Round 6
// 623.357 us; speedup vs baseline: 2.9152x; 1.4225x over previous
//
#include <hip/hip_runtime.h>
#include <hip/hip_bf16.h>

// Sizes (fixed for this problem)
#define B_  4
#define S_  1024
#define DM_ 1024
#define H_  16
#define HD_ 64
#define I_  4096

typedef __attribute__((ext_vector_type(8))) short bf16x8;
typedef __attribute__((ext_vector_type(4))) float f32x4;

__device__ __forceinline__ float gelu_f(float x) {
  float x3 = x * x * x;
  return 0.5f * x * (1.0f + tanhf(0.7978845608028654f * (x + 0.044715f * x3)));
}

__device__ __forceinline__ unsigned short f32_to_bf16(float f) {
  unsigned int u = __float_as_uint(f);
  unsigned int rounding = 0x7FFFu + ((u >> 16) & 1u);
  u += rounding;
  return (unsigned short)(u >> 16);
}

__device__ __forceinline__ float bf16_to_f32(unsigned short u) {
  return __uint_as_float(((unsigned int)u) << 16);
}

// split f32 -> hi bf16 + lo bf16 (v ~= hi + lo, residual ~1.5e-5 rel)
__device__ __forceinline__ void split_bf16(float v, unsigned short& h, unsigned short& l) {
  h = f32_to_bf16(v);
  l = f32_to_bf16(v - bf16_to_f32(h));
}

// ---------------------------------------------------------------------------
// f32 -> bf16 elementwise convert (for x)
// ---------------------------------------------------------------------------
__global__ __launch_bounds__(256) void cvt_bf16_kernel(
    const float* __restrict__ in, unsigned short* __restrict__ out, int n4)
{
  int i = blockIdx.x * 256 + threadIdx.x;
  if (i < n4) {
    float4 v = *reinterpret_cast<const float4*>(&in[(size_t)i * 4]);
    ushort4 o;
    o.x = f32_to_bf16(v.x); o.y = f32_to_bf16(v.y);
    o.z = f32_to_bf16(v.z); o.w = f32_to_bf16(v.w);
    *reinterpret_cast<ushort4*>(&out[(size_t)i * 4]) = o;
  }
}

// ---------------------------------------------------------------------------
// Transpose + convert: W [K,N] f32 -> WT [N,K] bf16. 64x64 tiles, 256 thr.
// ---------------------------------------------------------------------------
__global__ __launch_bounds__(256) void tcvt_kernel(
    const float* __restrict__ W, unsigned short* __restrict__ WT, int K, int N)
{
  __shared__ float tile[64][65];
  const int tid = threadIdx.x;
  const int k0 = blockIdx.y * 64, n0 = blockIdx.x * 64;
#pragma unroll
  for (int i = 0; i < 4; ++i) {
    int u = tid + i * 256;
    int kr = u >> 4, nc = (u & 15) * 4;
    float4 v = *reinterpret_cast<const float4*>(&W[(size_t)(k0 + kr) * N + n0 + nc]);
    tile[kr][nc + 0] = v.x; tile[kr][nc + 1] = v.y;
    tile[kr][nc + 2] = v.z; tile[kr][nc + 3] = v.w;
  }
  __syncthreads();
  int n = tid >> 2, ks = (tid & 3) * 16;
  unsigned short* dst = &WT[(size_t)(n0 + n) * K + k0 + ks];
#pragma unroll
  for (int j = 0; j < 4; ++j) {
    ushort4 o;
    o.x = f32_to_bf16(tile[ks + j * 4 + 0][n]);
    o.y = f32_to_bf16(tile[ks + j * 4 + 1][n]);
    o.z = f32_to_bf16(tile[ks + j * 4 + 2][n]);
    o.w = f32_to_bf16(tile[ks + j * 4 + 3][n]);
    *reinterpret_cast<ushort4*>(&dst[j * 4]) = o;
  }
}

// ---------------------------------------------------------------------------
// Transpose (f32 -> f32): Wqk [K,N] -> WqkT [N,K]
// ---------------------------------------------------------------------------
__global__ __launch_bounds__(256) void t_f32_kernel(
    const float* __restrict__ W, float* __restrict__ WT, int K, int N)
{
  __shared__ float tile[64][65];
  const int tid = threadIdx.x;
  const int k0 = blockIdx.y * 64, n0 = blockIdx.x * 64;
#pragma unroll
  for (int i = 0; i < 4; ++i) {
    int u = tid + i * 256;
    int kr = u >> 4, nc = (u & 15) * 4;
    float4 v = *reinterpret_cast<const float4*>(&W[(size_t)(k0 + kr) * N + n0 + nc]);
    tile[kr][nc + 0] = v.x; tile[kr][nc + 1] = v.y;
    tile[kr][nc + 2] = v.z; tile[kr][nc + 3] = v.w;
  }
  __syncthreads();
  int n = tid >> 2, ks = (tid & 3) * 16;
  float* dst = &WT[(size_t)(n0 + n) * K + k0 + ks];
#pragma unroll
  for (int j = 0; j < 4; ++j) {
    float4 o = make_float4(tile[ks + j * 4 + 0][n], tile[ks + j * 4 + 1][n],
                           tile[ks + j * 4 + 2][n], tile[ks + j * 4 + 3][n]);
    *reinterpret_cast<float4*>(&dst[j * 4]) = o;
  }
}

// ---------------------------------------------------------------------------
// bf16 MFMA GEMM: C = [gelu](A @ B + bias) [+ res]
// A [M,K] bf16 row-major; BT [N,K] bf16 row-major.
// 128x128 tile, BK=32, 4 waves; wave = 32 rows x 128 cols (2x8 fragments).
// ---------------------------------------------------------------------------
template<bool GELU, bool RES, bool RESBF16, bool BHSD, bool OBF16>
__global__ __launch_bounds__(256) void gemm_mfma_kernel(
    const unsigned short* __restrict__ A, const unsigned short* __restrict__ BT,
    const float* __restrict__ bias, const void* __restrict__ res,
    void* __restrict__ C, int M, int N, int K)
{
  __shared__ unsigned short As[128][40];
  __shared__ unsigned short Bs[128][40];
  const int tid = threadIdx.x;
  const int wid = tid >> 6;
  const int lane = tid & 63;
  const int bm = blockIdx.y * 128;
  const int bn = blockIdx.x * 128;
  const int l15 = lane & 15;
  const int kb = (lane >> 4) * 8;

  f32x4 acc[2][8];
#pragma unroll
  for (int mi = 0; mi < 2; ++mi)
#pragma unroll
    for (int ni = 0; ni < 8; ++ni) acc[mi][ni] = (f32x4){0.f, 0.f, 0.f, 0.f};

  for (int k0 = 0; k0 < K; k0 += 32) {
#pragma unroll
    for (int i = 0; i < 2; ++i) {
      int u = tid + i * 256;
      int row = u >> 2, seg = (u & 3) * 8;
      int4 va = *reinterpret_cast<const int4*>(&A[(size_t)(bm + row) * K + k0 + seg]);
      *reinterpret_cast<int4*>(&As[row][seg]) = va;
      int4 vb = *reinterpret_cast<const int4*>(&BT[(size_t)(bn + row) * K + k0 + seg]);
      *reinterpret_cast<int4*>(&Bs[row][seg]) = vb;
    }
    __syncthreads();

    bf16x8 af[2], bf[8];
#pragma unroll
    for (int mi = 0; mi < 2; ++mi)
      af[mi] = *reinterpret_cast<const bf16x8*>(&As[wid * 32 + mi * 16 + l15][kb]);
#pragma unroll
    for (int ni = 0; ni < 8; ++ni)
      bf[ni] = *reinterpret_cast<const bf16x8*>(&Bs[ni * 16 + l15][kb]);
#pragma unroll
    for (int mi = 0; mi < 2; ++mi)
#pragma unroll
      for (int ni = 0; ni < 8; ++ni)
        acc[mi][ni] = __builtin_amdgcn_mfma_f32_16x16x32_bf16(
            af[mi], bf[ni], acc[mi][ni], 0, 0, 0);
    __syncthreads();
  }

#pragma unroll
  for (int mi = 0; mi < 2; ++mi) {
#pragma unroll
    for (int ni = 0; ni < 8; ++ni) {
      int gcol = bn + ni * 16 + l15;
      float bsv = bias[gcol];
#pragma unroll
      for (int r = 0; r < 4; ++r) {
        int grow = bm + wid * 32 + mi * 16 + (lane >> 4) * 4 + r;
        float val = acc[mi][ni][r] + bsv;
        if (GELU) val = gelu_f(val);
        if (RES) {
          if (RESBF16) val += bf16_to_f32(((const unsigned short*)res)[(size_t)grow * N + gcol]);
          else         val += ((const float*)res)[(size_t)grow * N + gcol];
        }
        if (BHSD) {
          int bb = grow >> 10, ss = grow & 1023, hh = gcol >> 6, dd = gcol & 63;
          size_t adr = ((size_t)(bb * H_ + hh) * S_ + ss) * HD_ + dd;
          if (OBF16) ((unsigned short*)C)[adr] = f32_to_bf16(val);
          else       ((float*)C)[adr] = val;
        } else if (OBF16) {
          ((unsigned short*)C)[(size_t)grow * N + gcol] = f32_to_bf16(val);
        } else {
          ((float*)C)[(size_t)grow * N + gcol] = val;
        }
      }
    }
  }
}

// ---------------------------------------------------------------------------
// Split-f32 MFMA GEMM (3-product): C = A @ B + bias, near-f32 precision.
// A [M,K] f32; BT [N,K] f32. Output f32 scattered to [B,H,S,HD] (qk proj).
// ---------------------------------------------------------------------------
__global__ __launch_bounds__(256) void gemm_mfma3_kernel(
    const float* __restrict__ A, const float* __restrict__ BT,
    const float* __restrict__ bias, float* __restrict__ C, int M, int N, int K)
{
  __shared__ unsigned short Ah[128][40], Al[128][40];
  __shared__ unsigned short Bh[128][40], Bl[128][40];
  const int tid = threadIdx.x;
  const int wid = tid >> 6;
  const int lane = tid & 63;
  const int bm = blockIdx.y * 128;
  const int bn = blockIdx.x * 128;
  const int l15 = lane & 15;
  const int kb = (lane >> 4) * 8;

  f32x4 acc[2][8];
#pragma unroll
  for (int mi = 0; mi < 2; ++mi)
#pragma unroll
    for (int ni = 0; ni < 8; ++ni) acc[mi][ni] = (f32x4){0.f, 0.f, 0.f, 0.f};

  for (int k0 = 0; k0 < K; k0 += 32) {
#pragma unroll
    for (int i = 0; i < 2; ++i) {
      int u = tid + i * 256;
      int row = u >> 2, seg = (u & 3) * 8;
#pragma unroll
      for (int half = 0; half < 2; ++half) {
        float4 va = *reinterpret_cast<const float4*>(&A[(size_t)(bm + row) * K + k0 + seg + half * 4]);
        ushort4 h4, l4;
        split_bf16(va.x, h4.x, l4.x); split_bf16(va.y, h4.y, l4.y);
        split_bf16(va.z, h4.z, l4.z); split_bf16(va.w, h4.w, l4.w);
        *reinterpret_cast<ushort4*>(&Ah[row][seg + half * 4]) = h4;
        *reinterpret_cast<ushort4*>(&Al[row][seg + half * 4]) = l4;
        float4 vb = *reinterpret_cast<const float4*>(&BT[(size_t)(bn + row) * K + k0 + seg + half * 4]);
        split_bf16(vb.x, h4.x, l4.x); split_bf16(vb.y, h4.y, l4.y);
        split_bf16(vb.z, h4.z, l4.z); split_bf16(vb.w, h4.w, l4.w);
        *reinterpret_cast<ushort4*>(&Bh[row][seg + half * 4]) = h4;
        *reinterpret_cast<ushort4*>(&Bl[row][seg + half * 4]) = l4;
      }
    }
    __syncthreads();

    bf16x8 ah[2], al[2];
#pragma unroll
    for (int mi = 0; mi < 2; ++mi) {
      ah[mi] = *reinterpret_cast<const bf16x8*>(&Ah[wid * 32 + mi * 16 + l15][kb]);
      al[mi] = *reinterpret_cast<const bf16x8*>(&Al[wid * 32 + mi * 16 + l15][kb]);
    }
#pragma unroll
    for (int ni = 0; ni < 8; ++ni) {
      bf16x8 bh = *reinterpret_cast<const bf16x8*>(&Bh[ni * 16 + l15][kb]);
      bf16x8 bl = *reinterpret_cast<const bf16x8*>(&Bl[ni * 16 + l15][kb]);
#pragma unroll
      for (int mi = 0; mi < 2; ++mi) {
        acc[mi][ni] = __builtin_amdgcn_mfma_f32_16x16x32_bf16(ah[mi], bh, acc[mi][ni], 0, 0, 0);
        acc[mi][ni] = __builtin_amdgcn_mfma_f32_16x16x32_bf16(al[mi], bh, acc[mi][ni], 0, 0, 0);
        acc[mi][ni] = __builtin_amdgcn_mfma_f32_16x16x32_bf16(ah[mi], bl, acc[mi][ni], 0, 0, 0);
      }
    }
    __syncthreads();
  }

#pragma unroll
  for (int mi = 0; mi < 2; ++mi) {
#pragma unroll
    for (int ni = 0; ni < 8; ++ni) {
      int gcol = bn + ni * 16 + l15;
      float bsv = bias[gcol];
#pragma unroll
      for (int r = 0; r < 4; ++r) {
        int grow = bm + wid * 32 + mi * 16 + (lane >> 4) * 4 + r;
        float val = acc[mi][ni][r] + bsv;
        int bb = grow >> 10, ss = grow & 1023, hh = gcol >> 6, dd = gcol & 63;
        C[((size_t)(bb * H_ + hh) * S_ + ss) * HD_ + dd] = val;
      }
    }
  }
}

// ---------------------------------------------------------------------------
// Fused attention: split-bf16 MFMA QK^T (near-f32) + rel + mask + softmax
// -> probs f32. Block = (b,h,16 q-rows), 4 waves; wave owns 32 k-cols per
// 128-col K-tile. Scores in MFMA C-layout regs: acc[kt 8][f 2] f32x4,
// element (kt,f,r): q = q0 + (lane>>4)*4 + r, k = 128kt + 32w + 16f + l15.
// LDS = 51.8 KB.
// ---------------------------------------------------------------------------
__global__ __launch_bounds__(256) void attn_mfma_kernel(
    const float* __restrict__ qk, const int* __restrict__ mask,
    const float* __restrict__ rel_emb, float* __restrict__ probs)
{
  __shared__ unsigned short Qh[16][72], Ql[16][72];
  __shared__ float Qf[16][68];
  __shared__ unsigned short Kh[128][72], Kl[128][72];
  __shared__ float relp[16][21];
  __shared__ float red1[4][16], red2[4][16];
  __shared__ int msk[1024];

  const int tid = threadIdx.x;
  const int b = blockIdx.z, h = blockIdx.y, qt = blockIdx.x;
  const float* qkbh = qk + (size_t)(b * H_ + h) * S_ * HD_;
  const int q0 = qt * 16;

  // stage mask row
  for (int i = tid; i < 1024; i += 256) msk[i] = mask[b * S_ + i];

  // stage Q (f32 + hi/lo bf16)
  {
    int row = tid >> 4, dq = (tid & 15) * 4;
    float4 v = *reinterpret_cast<const float4*>(&qkbh[(size_t)(q0 + row) * HD_ + dq]);
    Qf[row][dq + 0] = v.x; Qf[row][dq + 1] = v.y;
    Qf[row][dq + 2] = v.z; Qf[row][dq + 3] = v.w;
    ushort4 h4, l4;
    split_bf16(v.x, h4.x, l4.x); split_bf16(v.y, h4.y, l4.y);
    split_bf16(v.z, h4.z, l4.z); split_bf16(v.w, h4.w, l4.w);
    *reinterpret_cast<ushort4*>(&Qh[row][dq]) = h4;
    *reinterpret_cast<ushort4*>(&Ql[row][dq]) = l4;
  }
  __syncthreads();

  // relp[q][r] = Q[q,:] . rel_emb[r,:]  (f32)
  for (int idx = tid; idx < 16 * 21; idx += 256) {
    int q = idx / 21, r = idx - q * 21;
    float s = 0.f;
#pragma unroll 8
    for (int d = 0; d < 64; ++d) s += Qf[q][d] * rel_emb[r * 64 + d];
    relp[q][r] = s;
  }

  const int wv = tid >> 6;
  const int lane = tid & 63;
  const int l15 = lane & 15;
  const int hi4 = lane >> 4;
  const int kb = hi4 * 8;

  // A fragments (Q fixed for whole kernel)
  bf16x8 ah[2], al[2];
#pragma unroll
  for (int ks = 0; ks < 2; ++ks) {
    ah[ks] = *reinterpret_cast<const bf16x8*>(&Qh[l15][ks * 32 + kb]);
    al[ks] = *reinterpret_cast<const bf16x8*>(&Ql[l15][ks * 32 + kb]);
  }

  f32x4 acc[8][2];
#pragma unroll
  for (int t = 0; t < 8; ++t)
#pragma unroll
    for (int f = 0; f < 2; ++f) acc[t][f] = (f32x4){0.f, 0.f, 0.f, 0.f};

#pragma unroll
  for (int kt = 0; kt < 8; ++kt) {
    __syncthreads();
    // stage 128 K-rows, split hi/lo
#pragma unroll
    for (int i = 0; i < 8; ++i) {
      int u = tid + i * 256;
      int row = u >> 4, dq = (u & 15) * 4;
      float4 v = *reinterpret_cast<const float4*>(&qkbh[(size_t)(kt * 128 + row) * HD_ + dq]);
      ushort4 h4, l4;
      split_bf16(v.x, h4.x, l4.x); split_bf16(v.y, h4.y, l4.y);
      split_bf16(v.z, h4.z, l4.z); split_bf16(v.w, h4.w, l4.w);
      *reinterpret_cast<ushort4*>(&Kh[row][dq]) = h4;
      *reinterpret_cast<ushort4*>(&Kl[row][dq]) = l4;
    }
    __syncthreads();

#pragma unroll
    for (int f = 0; f < 2; ++f) {
      int cb = wv * 32 + f * 16;
#pragma unroll
      for (int ks = 0; ks < 2; ++ks) {
        bf16x8 bh = *reinterpret_cast<const bf16x8*>(&Kh[cb + l15][ks * 32 + kb]);
        bf16x8 bl = *reinterpret_cast<const bf16x8*>(&Kl[cb + l15][ks * 32 + kb]);
        acc[kt][f] = __builtin_amdgcn_mfma_f32_16x16x32_bf16(ah[ks], bh, acc[kt][f], 0, 0, 0);
        acc[kt][f] = __builtin_amdgcn_mfma_f32_16x16x32_bf16(al[ks], bh, acc[kt][f], 0, 0, 0);
        acc[kt][f] = __builtin_amdgcn_mfma_f32_16x16x32_bf16(ah[ks], bl, acc[kt][f], 0, 0, 0);
      }
    }
  }
  __syncthreads();   // relp/msk complete; K-tiles done

  // rel + mask; per-row max
  float mx[4] = {-3.0e38f, -3.0e38f, -3.0e38f, -3.0e38f};
#pragma unroll
  for (int t = 0; t < 8; ++t)
#pragma unroll
    for (int f = 0; f < 2; ++f)
#pragma unroll
      for (int r = 0; r < 4; ++r) {
        int ql = hi4 * 4 + r;
        int q = q0 + ql;
        int k = t * 128 + wv * 32 + f * 16 + l15;
        int d = k - q;
        int ridx = (d < -10 ? -10 : (d > 10 ? 10 : d)) + 10;
        float s = acc[t][f][r] + relp[ql][ridx];
        if (k == q || msk[k] == 0) s -= 10000.0f;
        acc[t][f][r] = s;
        mx[r] = fmaxf(mx[r], s);
      }
#pragma unroll
  for (int r = 0; r < 4; ++r) {
    mx[r] = fmaxf(mx[r], __shfl_xor(mx[r], 1));
    mx[r] = fmaxf(mx[r], __shfl_xor(mx[r], 2));
    mx[r] = fmaxf(mx[r], __shfl_xor(mx[r], 4));
    mx[r] = fmaxf(mx[r], __shfl_xor(mx[r], 8));
  }
  if (l15 == 0) {
#pragma unroll
    for (int r = 0; r < 4; ++r) red1[wv][hi4 * 4 + r] = mx[r];
  }
  __syncthreads();
  float mxq[4];
#pragma unroll
  for (int r = 0; r < 4; ++r) {
    int ql = hi4 * 4 + r;
    mxq[r] = fmaxf(fmaxf(red1[0][ql], red1[1][ql]), fmaxf(red1[2][ql], red1[3][ql]));
  }

  float sm[4] = {0.f, 0.f, 0.f, 0.f};
#pragma unroll
  for (int t = 0; t < 8; ++t)
#pragma unroll
    for (int f = 0; f < 2; ++f)
#pragma unroll
      for (int r = 0; r < 4; ++r) {
        float e = __expf(acc[t][f][r] - mxq[r]);
        acc[t][f][r] = e;
        sm[r] += e;
      }
#pragma unroll
  for (int r = 0; r < 4; ++r) {
    sm[r] += __shfl_xor(sm[r], 1);
    sm[r] += __shfl_xor(sm[r], 2);
    sm[r] += __shfl_xor(sm[r], 4);
    sm[r] += __shfl_xor(sm[r], 8);
  }
  if (l15 == 0) {
#pragma unroll
    for (int r = 0; r < 4; ++r) red2[wv][hi4 * 4 + r] = sm[r];
  }
  __syncthreads();
  float rinv[4];
#pragma unroll
  for (int r = 0; r < 4; ++r) {
    int ql = hi4 * 4 + r;
    rinv[r] = 1.0f / (red2[0][ql] + red2[1][ql] + red2[2][ql] + red2[3][ql]);
  }

  float* pb = probs + (size_t)(b * H_ + h) * S_ * S_;
#pragma unroll
  for (int t = 0; t < 8; ++t)
#pragma unroll
    for (int f = 0; f < 2; ++f)
#pragma unroll
      for (int r = 0; r < 4; ++r) {
        int q = q0 + hi4 * 4 + r;
        int k = t * 128 + wv * 32 + f * 16 + l15;
        pb[(size_t)q * S_ + k] = acc[t][f][r] * rinv[r];
      }
}

// ---------------------------------------------------------------------------
// PV via MFMA: ctxb[b,q,h*64+d] = sum_k P[q,k] * V[k,d]
// P staged f32->bf16; V (bf16 [B,H,S,HD]) staged transposed. Block 128q x 64d.
// ---------------------------------------------------------------------------
__global__ __launch_bounds__(256) void pv_mfma_kernel(
    const float* __restrict__ probs, const unsigned short* __restrict__ v,
    unsigned short* __restrict__ ctxb)
{
  __shared__ unsigned short Ps[128][40];
  __shared__ unsigned short Vt[64][40];
  const int tid = threadIdx.x;
  const int wid = tid >> 6;
  const int lane = tid & 63;
  const int l15 = lane & 15;
  const int kb = (lane >> 4) * 8;
  const int b = blockIdx.z, h = blockIdx.y, qt = blockIdx.x;
  const float* pr = probs + (size_t)(b * H_ + h) * S_ * S_ + (size_t)qt * 128 * S_;
  const unsigned short* vbh = v + (size_t)(b * H_ + h) * S_ * HD_;

  f32x4 acc[2][4];
#pragma unroll
  for (int mi = 0; mi < 2; ++mi)
#pragma unroll
    for (int ni = 0; ni < 4; ++ni) acc[mi][ni] = (f32x4){0.f, 0.f, 0.f, 0.f};

  for (int k0 = 0; k0 < S_; k0 += 32) {
    // stage P 128x32 (f32 -> bf16)
#pragma unroll
    for (int i = 0; i < 2; ++i) {
      int u = tid + i * 256;
      int row = u >> 2, seg = (u & 3) * 8;
#pragma unroll
      for (int half = 0; half < 2; ++half) {
        float4 p4 = *reinterpret_cast<const float4*>(&pr[(size_t)row * S_ + k0 + seg + half * 4]);
        ushort4 o;
        o.x = f32_to_bf16(p4.x); o.y = f32_to_bf16(p4.y);
        o.z = f32_to_bf16(p4.z); o.w = f32_to_bf16(p4.w);
        *reinterpret_cast<ushort4*>(&Ps[row][seg + half * 4]) = o;
      }
    }
    // stage V 32x64 transposed -> Vt[d][k]
    {
      int i = tid >> 4;          // hmm: 512 ushort4 units / 256 thr = 2
#pragma unroll
      for (int j = 0; j < 2; ++j) {
        int u = tid + j * 256;
        int krow = u >> 4, dq = (u & 15) * 4;
        ushort4 vv = *reinterpret_cast<const ushort4*>(&vbh[(size_t)(k0 + krow) * HD_ + dq]);
        Vt[dq + 0][krow] = vv.x;
        Vt[dq + 1][krow] = vv.y;
        Vt[dq + 2][krow] = vv.z;
        Vt[dq + 3][krow] = vv.w;
      }
      (void)i;
    }
    __syncthreads();

    bf16x8 af[2], bf[4];
#pragma unroll
    for (int mi = 0; mi < 2; ++mi)
      af[mi] = *reinterpret_cast<const bf16x8*>(&Ps[wid * 32 + mi * 16 + l15][kb]);
#pragma unroll
    for (int ni = 0; ni < 4; ++ni)
      bf[ni] = *reinterpret_cast<const bf16x8*>(&Vt[ni * 16 + l15][kb]);
#pragma unroll
    for (int mi = 0; mi < 2; ++mi)
#pragma unroll
      for (int ni = 0; ni < 4; ++ni)
        acc[mi][ni] = __builtin_amdgcn_mfma_f32_16x16x32_bf16(
            af[mi], bf[ni], acc[mi][ni], 0, 0, 0);
    __syncthreads();
  }

#pragma unroll
  for (int mi = 0; mi < 2; ++mi)
#pragma unroll
    for (int ni = 0; ni < 4; ++ni) {
      int dd = ni * 16 + l15;
#pragma unroll
      for (int r = 0; r < 4; ++r) {
        int q = qt * 128 + wid * 32 + mi * 16 + (lane >> 4) * 4 + r;
        ctxb[((size_t)b * S_ + q) * DM_ + h * HD_ + dd] = f32_to_bf16(acc[mi][ni][r]);
      }
    }
}

// ---------------------------------------------------------------------------
// Row LayerNorm (1024 cols), f32 in, f32 or bf16 out (safe in-place for f32)
// ---------------------------------------------------------------------------
template<bool OUTB16>
__global__ __launch_bounds__(256) void ln_kernel(
    const float* __restrict__ in, const float* __restrict__ g,
    const float* __restrict__ be, void* __restrict__ out)
{
  __shared__ float red[4];
  const int row = blockIdx.x, tid = threadIdx.x;
  const float* r = in + (size_t)row * DM_;
  float4 x = *reinterpret_cast<const float4*>(&r[tid * 4]);

  float s = x.x + x.y + x.z + x.w;
#pragma unroll
  for (int m = 1; m < 64; m <<= 1) s += __shfl_xor(s, m);
  if ((tid & 63) == 0) red[tid >> 6] = s;
  __syncthreads();
  float mean = (red[0] + red[1] + red[2] + red[3]) * (1.0f / 1024.0f);
  __syncthreads();

  float d0 = x.x - mean, d1 = x.y - mean, d2 = x.z - mean, d3 = x.w - mean;
  float sq = d0 * d0 + d1 * d1 + d2 * d2 + d3 * d3;
#pragma unroll
  for (int m = 1; m < 64; m <<= 1) sq += __shfl_xor(sq, m);
  if ((tid & 63) == 0) red[tid >> 6] = sq;
  __syncthreads();
  float var = (red[0] + red[1] + red[2] + red[3]) * (1.0f / 1024.0f);
  float rstd = rsqrtf(var + 1e-3f);

  int c = tid * 4;
  float4 gv = *reinterpret_cast<const float4*>(&g[c]);
  float4 bv = *reinterpret_cast<const float4*>(&be[c]);
  float y0 = d0 * rstd * gv.x + bv.x;
  float y1 = d1 * rstd * gv.y + bv.y;
  float y2 = d2 * rstd * gv.z + bv.z;
  float y3 = d3 * rstd * gv.w + bv.w;
  if (OUTB16) {
    ushort4 o;
    o.x = f32_to_bf16(y0); o.y = f32_to_bf16(y1);
    o.z = f32_to_bf16(y2); o.w = f32_to_bf16(y3);
    *reinterpret_cast<ushort4*>(&((unsigned short*)out)[(size_t)row * DM_ + c]) = o;
  } else {
    *reinterpret_cast<float4*>(&((float*)out)[(size_t)row * DM_ + c]) =
        make_float4(y0, y1, y2, y3);
  }
}

// ---------------------------------------------------------------------------
// Workspace plan (64 MB, offsets in MB; all overlays lifetime-checked):
//   0-8   WoT bf16   (prep -> Wo)
//   8-16  WiT bf16   (prep -> Wi)
//   16-18 WvT bf16   (prep -> Wv)
//   18-20 WapT bf16  (prep -> Wap)
//   20-28 xb bf16    (prep -> Wv),  then ctxb bf16 (pv -> Wap)
//   28-32 WqkT f32   (prep -> Wqk)
//   32-48 qkb f32    (Wqk -> attn), then y f32 (Wap -> ln1)
//   48-56 vb bf16    (Wv -> pv)
//   56-64 attnb bf16 (ln1 -> Wo)
//   16-48 interb bf16 (Wi -> Wo)   [WvT/WapT/ctxb/WqkT/y all dead by Wi]
//   t = outf (d_out); ln2 runs in place.
// ---------------------------------------------------------------------------
extern "C" void kernel_launch(void* const* d_in, const int* in_sizes, int n_in,
                              void* d_out, int out_size, void* d_ws, size_t ws_size,
                              hipStream_t stream) {
  const float* x    = (const float*)d_in[0];
  const int*   mask = (const int*)d_in[1];
  const float* Wqk  = (const float*)d_in[2];
  const float* bqk  = (const float*)d_in[3];
  const float* Wv   = (const float*)d_in[4];
  const float* bv   = (const float*)d_in[5];
  const float* rel  = (const float*)d_in[6];
  const float* Wap  = (const float*)d_in[7];
  const float* bap  = (const float*)d_in[8];
  const float* g1   = (const float*)d_in[9];
  const float* b1   = (const float*)d_in[10];
  const float* Wi   = (const float*)d_in[11];
  const float* bi   = (const float*)d_in[12];
  const float* Wo   = (const float*)d_in[13];
  const float* bo   = (const float*)d_in[14];
  const float* g2   = (const float*)d_in[15];
  const float* b2   = (const float*)d_in[16];

  char* wsb = (char*)d_ws;
  const size_t MB = 1048576;
  unsigned short* WoT    = (unsigned short*)(wsb + 0 * MB);
  unsigned short* WiT    = (unsigned short*)(wsb + 8 * MB);
  unsigned short* WvT    = (unsigned short*)(wsb + 16 * MB);
  unsigned short* WapT   = (unsigned short*)(wsb + 18 * MB);
  unsigned short* xb     = (unsigned short*)(wsb + 20 * MB);
  unsigned short* ctxb   = (unsigned short*)(wsb + 20 * MB);
  float*          WqkT   = (float*)(wsb + 28 * MB);
  float*          qkb    = (float*)(wsb + 32 * MB);
  float*          y      = (float*)(wsb + 32 * MB);
  unsigned short* vb     = (unsigned short*)(wsb + 48 * MB);
  unsigned short* attnb  = (unsigned short*)(wsb + 56 * MB);
  unsigned short* interb = (unsigned short*)(wsb + 16 * MB);

  float* outf  = (float*)d_out;        // out   [B,S,DM]  f32 (also t buffer)
  float* probs = outf + 4194304;       // probs [B,H,S,S] f32

  dim3 blk(256);
  // Preps
  cvt_bf16_kernel<<<4096, blk, 0, stream>>>(x, xb, 1048576);
  tcvt_kernel<<<dim3(16, 16), blk, 0, stream>>>(Wv,  WvT,  1024, 1024);
  tcvt_kernel<<<dim3(16, 16), blk, 0, stream>>>(Wap, WapT, 1024, 1024);
  tcvt_kernel<<<dim3(64, 16), blk, 0, stream>>>(Wi,  WiT,  1024, 4096);
  tcvt_kernel<<<dim3(16, 64), blk, 0, stream>>>(Wo,  WoT,  4096, 1024);
  t_f32_kernel<<<dim3(16, 16), blk, 0, stream>>>(Wqk, WqkT, 1024, 1024);

  // q/k shared projection (split-f32 MFMA, near-f32) -> [B,H,S,HD] f32
  gemm_mfma3_kernel<<<dim3(8, 32), blk, 0, stream>>>(
      x, WqkT, bqk, qkb, 4096, 1024, 1024);
  // v projection (bf16 MFMA) -> [B,H,S,HD] bf16
  gemm_mfma_kernel<false, false, false, true, true><<<dim3(8, 32), blk, 0, stream>>>(
      xb, WvT, bv, nullptr, vb, 4096, 1024, 1024);
  // scores (split MFMA) + rel + mask + softmax -> probs f32
  attn_mfma_kernel<<<dim3(64, 16, 4), blk, 0, stream>>>(qkb, mask, rel, probs);
  // ctx = probs @ v (bf16 MFMA) -> bf16 [B,S,DM]
  pv_mfma_kernel<<<dim3(8, 16, 4), blk, 0, stream>>>(probs, vb, ctxb);
  // y = gelu(ctx @ Wap + bap) + x
  gemm_mfma_kernel<true, true, false, false, false><<<dim3(8, 32), blk, 0, stream>>>(
      ctxb, WapT, bap, x, y, 4096, 1024, 1024);
  // attnb = LN(y)*g1+b1 (bf16)
  ln_kernel<true><<<4096, blk, 0, stream>>>(y, g1, b1, attnb);
  // inter = gelu(attn @ Wi + bi) (bf16)
  gemm_mfma_kernel<true, false, false, false, true><<<dim3(32, 32), blk, 0, stream>>>(
      attnb, WiT, bi, nullptr, interb, 4096, 4096, 1024);
  // outf = gelu(inter @ Wo + bo) + attn   (t lives in d_out)
  gemm_mfma_kernel<true, true, true, false, false><<<dim3(8, 32), blk, 0, stream>>>(
      interb, WoT, bo, attnb, outf, 4096, 1024, 4096);
  // out = LN(t)*g2+b2 (f32, in place)
  ln_kernel<false><<<4096, blk, 0, stream>>>(outf, g2, b2, outf);
}